// Round 1
// baseline (7533.923 us; speedup 1.0000x reference)
//
#include <hip/hip_runtime.h>
#include <hip/hip_bf16.h>

// LSTM: B=64, T=512, I=512, H=512. Output = final h [64,512] fp32.
//
// Strategy:
//   - 4 clusters x 32 WGs (128 WGs x 256 thr). Cluster = 16 batches.
//   - Each WG owns 64 gate-columns (4 gates x 16 h-cols), full K=1024,
//     with its W slice (128KB bf16) held IN REGISTERS (32 mfma B-frags/lane).
//   - Per step: waves 0,1 compute the x-part (K 0..511) BEFORE the cluster
//     sync (hides it under the previous step's tail); waves 2,3 compute the
//     h-part (K 512..1023) after the sync; 4KB LDS reduction merges halves.
//   - Gate pairing: even waves (f,o), odd waves (i,C); one 1KB LDS exchange
//     of p = sigmoid(i)*tanh(C); c stays in wave-0 registers.
//   - Cross-WG sync: per-cluster monotonic counter, release/acquire via
//     __builtin_amdgcn_fence(agent) + relaxed agent atomics. 128 blocks
//     <= 256 CUs -> all co-resident, spin is safe.

#define T_STEPS 512
#define NBATCH  64
#define HID     512
#define INPD    512
#define NCL     4
#define WPC     32     // workgroups per cluster
#define CLB     16     // batches per cluster

typedef __attribute__((ext_vector_type(8))) short bf16x8;
typedef __attribute__((ext_vector_type(4))) float f32x4;
typedef __attribute__((ext_vector_type(4))) short s16x4;

// workspace layout (bytes)
#define WS_CTR_OFF 0                       // 4 counters, 256B apart
#define WS_W_OFF   1024                    // W_perm bf16 [2048 cols][1024 k] = 4MB
#define WS_H_OFF   (WS_W_OFF + 2048*1024*2) // h double buffer [2][64][512] bf16 = 128KB

__device__ __forceinline__ short f2bf(float f) {
    unsigned u = __float_as_uint(f);
    unsigned r = u + 0x7fffu + ((u >> 16) & 1u);   // round-to-nearest-even
    return (short)(r >> 16);
}
__device__ __forceinline__ float sigmf(float x) { return 1.f / (1.f + __expf(-x)); }
__device__ __forceinline__ float tanhf2(float x) {
    float a = fabsf(x);
    float e = __expf(-2.f * a);
    float r = (1.f - e) / (1.f + e);
    return x < 0.f ? -r : r;
}

__global__ void prep_zero(int* ctr, short* hbuf) {
    int gid = blockIdx.x * 256 + threadIdx.x;      // 64*256 = 16384 threads
    ((int*)hbuf)[gid] = 0;                         // zero hbuf[0]: 64KB
    if (blockIdx.x == 0 && threadIdx.x < NCL) ctr[threadIdx.x * 64] = 0;
}

// W_perm[col][k], col = w*64 + g*16 + hcl  (hc = w*16 + hcl), k in [0,1024)
__global__ void prep_w(const float* __restrict__ Wf, const float* __restrict__ Wi,
                       const float* __restrict__ Wo, const float* __restrict__ Wc,
                       short* __restrict__ wperm) {
    int gid  = blockIdx.x * 256 + threadIdx.x;     // 2048*256 threads, 4 elems each
    int base = gid * 4;                            // covers 2048*1024
    int col  = base >> 10;
    int k0   = base & 1023;
    int w    = col >> 6, n = col & 63;
    int g    = n >> 4,  hcl = n & 15;
    int hc   = w * 16 + hcl;
    const float* Wg = (g == 0) ? Wf : (g == 1) ? Wi : (g == 2) ? Wo : Wc;
    s16x4 t;
#pragma unroll
    for (int j = 0; j < 4; ++j)
        t[j] = f2bf(Wg[(k0 + j) * 512 + hc]);      // W_g is [1024][512] row-major
    *(s16x4*)(wperm + base) = t;
}

__launch_bounds__(256, 1)
__global__ void lstm_rec(const float* __restrict__ x,     // [B][T][I] fp32
                         const float* __restrict__ bf_g, const float* __restrict__ bi_g,
                         const float* __restrict__ bo_g, const float* __restrict__ bc_g,
                         const short* __restrict__ wperm,
                         short* __restrict__ hbuf,         // [2][64][512] bf16
                         int* __restrict__ ctrbase,
                         float* __restrict__ out)          // [64][512] fp32
{
    const int tid  = threadIdx.x;
    const int wv   = tid >> 6;
    const int lane = tid & 63;
    const int bid  = blockIdx.x;
    const int cl   = bid & (NCL - 1);   // cluster: bids == cl (mod 4) -> XCDs {cl, cl+4}
    const int w    = bid >> 2;          // 0..31: which 16 h-cols of 512
    int* ctr = ctrbase + cl * 64;

    const int r16 = lane & 15;          // tile row (A) / tile col (B,D)
    const int kg  = lane >> 4;          // k-group 0..3

    const int gA    = wv & 1;           // even waves: gates (f=0, o=2); odd: (i=1, C=3)
    const int kbase = (wv >> 1) * 512;  // waves 0,1: x half; waves 2,3: h half

    // ---- W fragments resident in registers: 32 x bf16x8 = 128 VGPR ----
    bf16x8 wfrA[16], wfrB[16];
    {
        const int colA = w * 64 + gA * 16 + r16;
        const int colB = w * 64 + (gA + 2) * 16 + r16;
#pragma unroll
        for (int kk = 0; kk < 16; ++kk) {
            int k = kbase + kk * 32 + kg * 8;
            wfrA[kk] = *(const bf16x8*)(wperm + colA * 1024 + k);
            wfrB[kk] = *(const bf16x8*)(wperm + colB * 1024 + k);
        }
    }

    const int hc = w * 16 + r16;
    float biasA = 0.f, biasB = 0.f;
    if (wv == 0)      { biasA = bf_g[hc]; biasB = bo_g[hc]; }
    else if (wv == 1) { biasA = bi_g[hc]; biasB = bc_g[hc]; }

    __shared__ float red[2][2][64][4];  // [wv-2][tile][lane][j]  (4KB)
    __shared__ float pbuf[64][4];       // i*tanh(C) exchange     (1KB)

    const int batch0 = cl * CLB;
    const int arow   = batch0 + r16;    // A-operand row = batch

    f32x4 cst = {0.f, 0.f, 0.f, 0.f};   // c state (wave 0)
    bool dead = false;

    for (int s = 0; s < T_STEPS; ++s) {
        f32x4 accA = {0.f,0.f,0.f,0.f}, accB = {0.f,0.f,0.f,0.f};

        // ---- x-part: independent of h, runs before the sync ----
        if (wv < 2) {
            const float* xp = x + ((size_t)arow * T_STEPS + s) * INPD + kg * 8;
#pragma unroll
            for (int kk = 0; kk < 16; ++kk) {
                f32x4 lo = *(const f32x4*)(xp + kk * 32);
                f32x4 hi = *(const f32x4*)(xp + kk * 32 + 4);
                bf16x8 a;
                a[0]=f2bf(lo[0]); a[1]=f2bf(lo[1]); a[2]=f2bf(lo[2]); a[3]=f2bf(lo[3]);
                a[4]=f2bf(hi[0]); a[5]=f2bf(hi[1]); a[6]=f2bf(hi[2]); a[7]=f2bf(hi[3]);
                accA = __builtin_amdgcn_mfma_f32_16x16x32_bf16(a, wfrA[kk], accA, 0, 0, 0);
                accB = __builtin_amdgcn_mfma_f32_16x16x32_bf16(a, wfrB[kk], accB, 0, 0, 0);
            }
        }

        // ---- cluster sync: wait for h_s from all 32 WGs ----
        if (s > 0) {
            if (tid == 0 && !dead) {
                int target = WPC * s;
                int polls = 0;
                while (__hip_atomic_load(ctr, __ATOMIC_RELAXED, __HIP_MEMORY_SCOPE_AGENT) < target) {
                    __builtin_amdgcn_s_sleep(1);
                    if (++polls > (1 << 20)) { dead = true; break; }  // no-hang bailout
                }
            }
            __syncthreads();
            __builtin_amdgcn_fence(__ATOMIC_ACQUIRE, "agent");   // inv L1/L2
        }

        // ---- h-part ----
        if (wv >= 2) {
            const short* hp = hbuf + (s & 1) * (NBATCH * HID) + arow * HID + kg * 8;
#pragma unroll
            for (int kk = 0; kk < 16; ++kk) {
                bf16x8 a = *(const bf16x8*)(hp + kk * 32);
                accA = __builtin_amdgcn_mfma_f32_16x16x32_bf16(a, wfrA[kk], accA, 0, 0, 0);
                accB = __builtin_amdgcn_mfma_f32_16x16x32_bf16(a, wfrB[kk], accB, 0, 0, 0);
            }
            *(f32x4*)&red[wv - 2][0][lane][0] = accA;
            *(f32x4*)&red[wv - 2][1][lane][0] = accB;
        }
        __syncthreads();

        // ---- merge K-halves, gates ----
        f32x4 fvv, ovv;
        if (wv == 1) {
            accA += *(const f32x4*)&red[1][0][lane][0];
            accB += *(const f32x4*)&red[1][1][lane][0];
            f32x4 p;
#pragma unroll
            for (int j = 0; j < 4; ++j) {
                float iv = sigmf(accA[j] + biasA);
                float cg = tanhf2(accB[j] + biasB);
                p[j] = iv * cg;
            }
            *(f32x4*)&pbuf[lane][0] = p;
        } else if (wv == 0) {
            accA += *(const f32x4*)&red[0][0][lane][0];
            accB += *(const f32x4*)&red[0][1][lane][0];
#pragma unroll
            for (int j = 0; j < 4; ++j) {
                fvv[j] = sigmf(accA[j] + biasA);
                ovv[j] = sigmf(accB[j] + biasB);
            }
        }
        __syncthreads();

        // ---- c,h update + publish ----
        if (wv == 0) {
            f32x4 p = *(const f32x4*)&pbuf[lane][0];
            short* hd = hbuf + ((s + 1) & 1) * (NBATCH * HID);
#pragma unroll
            for (int j = 0; j < 4; ++j) {
                float c = fvv[j] * cst[j] + p[j];
                cst[j] = c;
                float h = ovv[j] * tanhf2(c);
                int brow = batch0 + kg * 4 + j;   // D row = 4*kg + j
                hd[brow * HID + hc] = f2bf(h);
                if (s == T_STEPS - 1) out[brow * HID + hc] = h;
            }
            __builtin_amdgcn_fence(__ATOMIC_RELEASE, "agent");   // wb L2 -> visible
        }
        if (tid == 0)
            __hip_atomic_fetch_add(ctr, 1, __ATOMIC_RELAXED, __HIP_MEMORY_SCOPE_AGENT);
    }
}

extern "C" void kernel_launch(void* const* d_in, const int* in_sizes, int n_in,
                              void* d_out, int out_size, void* d_ws, size_t ws_size,
                              hipStream_t stream) {
    const float* x  = (const float*)d_in[0];
    const float* Wf = (const float*)d_in[1];
    const float* bf = (const float*)d_in[2];
    const float* Wi = (const float*)d_in[3];
    const float* bi = (const float*)d_in[4];
    const float* Wo = (const float*)d_in[5];
    const float* bo = (const float*)d_in[6];
    const float* Wc = (const float*)d_in[7];
    const float* bc = (const float*)d_in[8];

    char*  ws    = (char*)d_ws;
    int*   ctr   = (int*)(ws + WS_CTR_OFF);
    short* wperm = (short*)(ws + WS_W_OFF);
    short* hbuf  = (short*)(ws + WS_H_OFF);

    prep_zero<<<dim3(64),   dim3(256), 0, stream>>>(ctr, hbuf);
    prep_w   <<<dim3(2048), dim3(256), 0, stream>>>(Wf, Wi, Wo, Wc, wperm);
    lstm_rec <<<dim3(NCL * WPC), dim3(256), 0, stream>>>(
        x, bf, bi, bo, bc, wperm, hbuf, ctr, (float*)d_out);
}

// Round 2
// 5147.726 us; speedup vs baseline: 1.4635x; 1.4635x over previous
//
#include <hip/hip_runtime.h>
#include <hip/hip_bf16.h>

// LSTM: B=64, T=512, I=512, H=512. Output = final h [64,512] fp32.
//
// Strategy (round 2):
//   - 4 clusters x 32 WGs (128 WGs x 256 thr). Cluster = 16 batches.
//   - Each WG owns 64 gate-columns (4 gates x 16 h-cols), full K=1024,
//     W slice (128KB bf16) held in registers (32 mfma B-frags/lane).
//   - Waves 0,1: x-part (K 0..511) before the cluster sync; waves 2,3:
//     h-part after the sync; 4KB LDS reduction merges halves.
//   - NEW: no agent fences (buffer_wbl2 / buffer_inv were forcing h through
//     HBM and nuking L2 every step -> 16.7us/step). All cross-WG traffic
//     (h values + counter) now moves via RELAXED AGENT-SCOPE ATOMICS, which
//     lower to sc0/sc1 cache-bypass ops served by the MALL (L3) coherence
//     point. Publisher orders h-stores before the counter bump with an
//     explicit s_waitcnt vmcnt(0) (write-through ack == visibility).
//     x and W keep plain cached loads and now stay L2-resident.

#define T_STEPS 512
#define NBATCH  64
#define HID     512
#define INPD    512
#define NCL     4
#define WPC     32     // workgroups per cluster
#define CLB     16     // batches per cluster

typedef __attribute__((ext_vector_type(8))) short bf16x8;
typedef __attribute__((ext_vector_type(4))) float f32x4;
typedef __attribute__((ext_vector_type(4))) short s16x4;
typedef __attribute__((ext_vector_type(2))) unsigned long long u64x2;

// workspace layout (bytes)
#define WS_CTR_OFF 0                        // 4 counters, 256B apart
#define WS_W_OFF   1024                     // W_perm bf16 [2048 cols][1024 k] = 4MB
#define WS_H_OFF   (WS_W_OFF + 2048*1024*2) // h double buffer [2][64][512] bf16 = 128KB

__device__ __forceinline__ short f2bf(float f) {
    unsigned u = __float_as_uint(f);
    unsigned r = u + 0x7fffu + ((u >> 16) & 1u);   // round-to-nearest-even
    return (short)(r >> 16);
}
__device__ __forceinline__ float sigmf(float x) { return 1.f / (1.f + __expf(-x)); }
__device__ __forceinline__ float tanhf2(float x) {
    float a = fabsf(x);
    float e = __expf(-2.f * a);
    float r = (1.f - e) / (1.f + e);
    return x < 0.f ? -r : r;
}

__global__ void prep_zero(int* ctr, short* hbuf) {
    int gid = blockIdx.x * 256 + threadIdx.x;      // 64*256 = 16384 threads
    ((int*)hbuf)[gid] = 0;                         // zero hbuf[0]: 64KB
    if (blockIdx.x == 0 && threadIdx.x < NCL) ctr[threadIdx.x * 64] = 0;
}

// W_perm[col][k], col = w*64 + g*16 + hcl  (hc = w*16 + hcl), k in [0,1024)
__global__ void prep_w(const float* __restrict__ Wf, const float* __restrict__ Wi,
                       const float* __restrict__ Wo, const float* __restrict__ Wc,
                       short* __restrict__ wperm) {
    int gid  = blockIdx.x * 256 + threadIdx.x;     // 2048*256 threads, 4 elems each
    int base = gid * 4;                            // covers 2048*1024
    int col  = base >> 10;
    int k0   = base & 1023;
    int w    = col >> 6, n = col & 63;
    int g    = n >> 4,  hcl = n & 15;
    int hc   = w * 16 + hcl;
    const float* Wg = (g == 0) ? Wf : (g == 1) ? Wi : (g == 2) ? Wo : Wc;
    s16x4 t;
#pragma unroll
    for (int j = 0; j < 4; ++j)
        t[j] = f2bf(Wg[(k0 + j) * 512 + hc]);      // W_g is [1024][512] row-major
    *(s16x4*)(wperm + base) = t;
}

__launch_bounds__(256, 1)
__global__ void lstm_rec(const float* __restrict__ x,     // [B][T][I] fp32
                         const float* __restrict__ bf_g, const float* __restrict__ bi_g,
                         const float* __restrict__ bo_g, const float* __restrict__ bc_g,
                         const short* __restrict__ wperm,
                         short* __restrict__ hbuf,         // [2][64][512] bf16
                         int* __restrict__ ctrbase,
                         float* __restrict__ out)          // [64][512] fp32
{
    const int tid  = threadIdx.x;
    const int wv   = tid >> 6;
    const int lane = tid & 63;
    const int bid  = blockIdx.x;
    const int cl   = bid & (NCL - 1);   // cluster: bids == cl (mod 4)
    const int w    = bid >> 2;          // 0..31: which 16 h-cols of 512
    int* ctr = ctrbase + cl * 64;

    const int r16 = lane & 15;          // tile row (A) / tile col (B,D)
    const int kg  = lane >> 4;          // k-group 0..3

    const int gA    = wv & 1;           // even waves: gates (f=0, o=2); odd: (i=1, C=3)
    const int kbase = (wv >> 1) * 512;  // waves 0,1: x half; waves 2,3: h half

    // ---- W fragments resident in registers: 32 x bf16x8 = 128 VGPR ----
    bf16x8 wfrA[16], wfrB[16];
    {
        const int colA = w * 64 + gA * 16 + r16;
        const int colB = w * 64 + (gA + 2) * 16 + r16;
#pragma unroll
        for (int kk = 0; kk < 16; ++kk) {
            int k = kbase + kk * 32 + kg * 8;
            wfrA[kk] = *(const bf16x8*)(wperm + colA * 1024 + k);
            wfrB[kk] = *(const bf16x8*)(wperm + colB * 1024 + k);
        }
    }

    const int hc = w * 16 + r16;
    float biasA = 0.f, biasB = 0.f;
    if (wv == 0)      { biasA = bf_g[hc]; biasB = bo_g[hc]; }
    else if (wv == 1) { biasA = bi_g[hc]; biasB = bc_g[hc]; }

    __shared__ float red[2][2][64][4];  // [wv-2][tile][lane][j]  (4KB)
    __shared__ float pbuf[64][4];       // i*tanh(C) exchange     (1KB)

    const int batch0 = cl * CLB;
    const int arow   = batch0 + r16;    // A-operand row = batch

    f32x4 cst = {0.f, 0.f, 0.f, 0.f};   // c state (wave 0)
    bool dead = false;

    for (int s = 0; s < T_STEPS; ++s) {
        f32x4 accA = {0.f,0.f,0.f,0.f}, accB = {0.f,0.f,0.f,0.f};

        // ---- x-part: independent of h, runs before the sync ----
        if (wv < 2) {
            const float* xp = x + ((size_t)arow * T_STEPS + s) * INPD + kg * 8;
#pragma unroll
            for (int kk = 0; kk < 16; ++kk) {
                f32x4 lo = *(const f32x4*)(xp + kk * 32);
                f32x4 hi = *(const f32x4*)(xp + kk * 32 + 4);
                bf16x8 a;
                a[0]=f2bf(lo[0]); a[1]=f2bf(lo[1]); a[2]=f2bf(lo[2]); a[3]=f2bf(lo[3]);
                a[4]=f2bf(hi[0]); a[5]=f2bf(hi[1]); a[6]=f2bf(hi[2]); a[7]=f2bf(hi[3]);
                accA = __builtin_amdgcn_mfma_f32_16x16x32_bf16(a, wfrA[kk], accA, 0, 0, 0);
                accB = __builtin_amdgcn_mfma_f32_16x16x32_bf16(a, wfrB[kk], accB, 0, 0, 0);
            }
        }

        // ---- cluster sync: wait for h_s from all 32 WGs (no fences) ----
        if (s > 0) {
            if (tid == 0 && !dead) {
                int target = WPC * s;
                int polls = 0;
                while (__hip_atomic_load(ctr, __ATOMIC_RELAXED, __HIP_MEMORY_SCOPE_AGENT) < target) {
                    __builtin_amdgcn_s_sleep(1);
                    if (++polls > (1 << 20)) { dead = true; break; }  // no-hang bailout
                }
            }
            __syncthreads();
        }

        // ---- h-part: agent-scope (MALL-coherent) loads, compiler-tracked ----
        if (wv >= 2) {
            const short* hp = hbuf + (s & 1) * (NBATCH * HID) + arow * HID + kg * 8;
#pragma unroll
            for (int kk = 0; kk < 16; ++kk) {
                u64x2 u;
                u[0] = __hip_atomic_load((const unsigned long long*)(hp + kk * 32),
                                         __ATOMIC_RELAXED, __HIP_MEMORY_SCOPE_AGENT);
                u[1] = __hip_atomic_load((const unsigned long long*)(hp + kk * 32 + 4),
                                         __ATOMIC_RELAXED, __HIP_MEMORY_SCOPE_AGENT);
                bf16x8 a = __builtin_bit_cast(bf16x8, u);
                accA = __builtin_amdgcn_mfma_f32_16x16x32_bf16(a, wfrA[kk], accA, 0, 0, 0);
                accB = __builtin_amdgcn_mfma_f32_16x16x32_bf16(a, wfrB[kk], accB, 0, 0, 0);
            }
            *(f32x4*)&red[wv - 2][0][lane][0] = accA;
            *(f32x4*)&red[wv - 2][1][lane][0] = accB;
        }
        __syncthreads();

        // ---- merge K-halves, gates ----
        f32x4 fvv, ovv;
        if (wv == 1) {
            accA += *(const f32x4*)&red[1][0][lane][0];
            accB += *(const f32x4*)&red[1][1][lane][0];
            f32x4 p;
#pragma unroll
            for (int j = 0; j < 4; ++j) {
                float iv = sigmf(accA[j] + biasA);
                float cg = tanhf2(accB[j] + biasB);
                p[j] = iv * cg;
            }
            *(f32x4*)&pbuf[lane][0] = p;
        } else if (wv == 0) {
            accA += *(const f32x4*)&red[0][0][lane][0];
            accB += *(const f32x4*)&red[0][1][lane][0];
#pragma unroll
            for (int j = 0; j < 4; ++j) {
                fvv[j] = sigmf(accA[j] + biasA);
                ovv[j] = sigmf(accB[j] + biasB);
            }
        }
        __syncthreads();

        // ---- c,h update + publish (agent-scope stores, then vmcnt-ordered add) ----
        if (wv == 0) {
            f32x4 p = *(const f32x4*)&pbuf[lane][0];
            short* hd = hbuf + ((s + 1) & 1) * (NBATCH * HID);
#pragma unroll
            for (int j = 0; j < 4; ++j) {
                float c = fvv[j] * cst[j] + p[j];
                cst[j] = c;
                float h = ovv[j] * tanhf2(c);
                int brow = batch0 + kg * 4 + j;   // D row = 4*kg + j
                __hip_atomic_store(&hd[brow * HID + hc], f2bf(h),
                                   __ATOMIC_RELAXED, __HIP_MEMORY_SCOPE_AGENT);
                if (s == T_STEPS - 1) out[brow * HID + hc] = h;
            }
        }
        // Drain the write-through stores to the coherence point (MALL) before
        // announcing this step. vmcnt ack on sc-flagged stores == visibility.
        asm volatile("s_waitcnt vmcnt(0)" ::: "memory");
        if (tid == 0)
            __hip_atomic_fetch_add(ctr, 1, __ATOMIC_RELAXED, __HIP_MEMORY_SCOPE_AGENT);
    }
}

extern "C" void kernel_launch(void* const* d_in, const int* in_sizes, int n_in,
                              void* d_out, int out_size, void* d_ws, size_t ws_size,
                              hipStream_t stream) {
    const float* x  = (const float*)d_in[0];
    const float* Wf = (const float*)d_in[1];
    const float* bf = (const float*)d_in[2];
    const float* Wi = (const float*)d_in[3];
    const float* bi = (const float*)d_in[4];
    const float* Wo = (const float*)d_in[5];
    const float* bo = (const float*)d_in[6];
    const float* Wc = (const float*)d_in[7];
    const float* bc = (const float*)d_in[8];

    char*  ws    = (char*)d_ws;
    int*   ctr   = (int*)(ws + WS_CTR_OFF);
    short* wperm = (short*)(ws + WS_W_OFF);
    short* hbuf  = (short*)(ws + WS_H_OFF);

    prep_zero<<<dim3(64),   dim3(256), 0, stream>>>(ctr, hbuf);
    prep_w   <<<dim3(2048), dim3(256), 0, stream>>>(Wf, Wi, Wo, Wc, wperm);
    lstm_rec <<<dim3(NCL * WPC), dim3(256), 0, stream>>>(
        x, bf, bi, bo, bc, wperm, hbuf, ctr, (float*)d_out);
}

// Round 3
// 4010.830 us; speedup vs baseline: 1.8784x; 1.2835x over previous
//
#include <hip/hip_runtime.h>
#include <hip/hip_bf16.h>

// LSTM: B=64, T=512, I=512, H=512. Output = final h [64,512] fp32.
//
// Round 3:
//   - 4 clusters x 32 WGs (128 WGs x 256 thr). Cluster = 16 batches.
//   - Each WG owns 64 gate-columns (4 gates x 16 h-cols), full K=1024,
//     W slice (128KB bf16) held in registers; asm "+v" anchors force
//     residency (round 2's VGPR_Count=96 proved the compiler was
//     re-loading W from L2 every step).
//   - SYNC = TAG-IN-WORD: h stored as u32 (tag<<16)|bf16, double-buffered.
//     Consumers poll-load the data itself and check tags; no counters, no
//     fences, no vmcnt drains, no contended lines. Publisher of h_{s+2}
//     transitively requires all WGs consumed h_s => 2 buffers suffice.
//     Replay-safe: stale tags from a previous replay carry bit-identical
//     values; 0xAA poison = tag 0xAAAA matches no s in [0,512).
//   - x-part (K 0..511) software-pipelined one step ahead by waves 0,1,
//     overlapping the consumers' (waves 2,3) poll+MFMA of the h-part.

#define T_STEPS 512
#define NBATCH  64
#define HID     512
#define INPD    512
#define NCL     4
#define WPC     32     // workgroups per cluster
#define CLB     16     // batches per cluster

typedef __attribute__((ext_vector_type(8))) short bf16x8;
typedef __attribute__((ext_vector_type(4))) float f32x4;
typedef __attribute__((ext_vector_type(4))) short s16x4;
typedef __attribute__((ext_vector_type(4))) unsigned u32x4;

// workspace layout (bytes)
#define WS_W_OFF   1024                     // W_perm bf16 [2048 cols][1024 k] = 4MB
#define WS_H_OFF   (WS_W_OFF + 2048*1024*2) // h tagged double buffer [2][64][512] u32 = 256KB

__device__ __forceinline__ short f2bf(float f) {
    unsigned u = __float_as_uint(f);
    unsigned r = u + 0x7fffu + ((u >> 16) & 1u);   // round-to-nearest-even
    return (short)(r >> 16);
}
__device__ __forceinline__ float sigmf(float x) { return 1.f / (1.f + __expf(-x)); }
__device__ __forceinline__ float tanhf2(float x) {
    float a = fabsf(x);
    float e = __expf(-2.f * a);
    float r = (1.f - e) / (1.f + e);
    return x < 0.f ? -r : r;
}

__global__ void prep_zero(unsigned* hbuf) {
    int gid = blockIdx.x * 256 + threadIdx.x;      // 128*256 = 32768 = 64*512
    hbuf[gid] = 0u;                                // buf0: tag=0, h=bf16(0)
}

// W_perm[col][k], col = w*64 + g*16 + hcl  (hc = w*16 + hcl), k in [0,1024)
__global__ void prep_w(const float* __restrict__ Wf, const float* __restrict__ Wi,
                       const float* __restrict__ Wo, const float* __restrict__ Wc,
                       short* __restrict__ wperm) {
    int gid  = blockIdx.x * 256 + threadIdx.x;     // 2048*256 threads, 4 elems each
    int base = gid * 4;                            // covers 2048*1024
    int col  = base >> 10;
    int k0   = base & 1023;
    int w    = col >> 6, n = col & 63;
    int g    = n >> 4,  hcl = n & 15;
    int hc   = w * 16 + hcl;
    const float* Wg = (g == 0) ? Wf : (g == 1) ? Wi : (g == 2) ? Wo : Wc;
    s16x4 t;
#pragma unroll
    for (int j = 0; j < 4; ++j)
        t[j] = f2bf(Wg[(k0 + j) * 512 + hc]);      // W_g is [1024][512] row-major
    *(s16x4*)(wperm + base) = t;
}

__launch_bounds__(256, 1)
__global__ void lstm_rec(const float* __restrict__ x,     // [B][T][I] fp32
                         const float* __restrict__ bf_g, const float* __restrict__ bi_g,
                         const float* __restrict__ bo_g, const float* __restrict__ bc_g,
                         const short* __restrict__ wperm,
                         unsigned* __restrict__ hbuf,      // [2][64][512] tagged u32
                         float* __restrict__ out)          // [64][512] fp32
{
    const int tid  = threadIdx.x;
    const int wv   = tid >> 6;
    const int lane = tid & 63;
    const int bid  = blockIdx.x;
    const int cl   = bid & (NCL - 1);   // cluster
    const int w    = bid >> 2;          // 0..31: which 16 h-cols of 512

    const int r16 = lane & 15;          // tile row (A) / tile col (B,D)
    const int kg  = lane >> 4;          // k-group 0..3

    const int gA    = wv & 1;           // even waves: gates (f=0, o=2); odd: (i=1, C=3)
    const int kbase = (wv >> 1) * 512;  // waves 0,1: x half; waves 2,3: h half

    // ---- W fragments resident in registers: 32 x bf16x8 = 128 VGPR ----
    bf16x8 wfrA[16], wfrB[16];
    {
        const int colA = w * 64 + gA * 16 + r16;
        const int colB = w * 64 + (gA + 2) * 16 + r16;
#pragma unroll
        for (int kk = 0; kk < 16; ++kk) {
            int k = kbase + kk * 32 + kg * 8;
            wfrA[kk] = *(const bf16x8*)(wperm + colA * 1024 + k);
            wfrB[kk] = *(const bf16x8*)(wperm + colB * 1024 + k);
        }
    }
    // Opaque-value anchor: forbids rematerializing W from memory inside the
    // loop (round 2: VGPR_Count=96 proved LLVM sank these loads).
#pragma unroll
    for (int kk = 0; kk < 16; ++kk) {
        asm volatile("" : "+v"(wfrA[kk]), "+v"(wfrB[kk]));
    }

    const int hc = w * 16 + r16;
    float biasA = 0.f, biasB = 0.f;
    if (wv == 0)      { biasA = bf_g[hc]; biasB = bo_g[hc]; }
    else if (wv == 1) { biasA = bi_g[hc]; biasB = bc_g[hc]; }

    __shared__ float red[2][2][64][4];  // [wv-2][tile][lane][j]  (4KB)
    __shared__ float pbuf[64][4];       // i*tanh(C) exchange     (1KB)

    const int batch0 = cl * CLB;
    const int arow   = batch0 + r16;    // A-operand row = batch

    // x-part accumulators, software-pipelined one step ahead (waves 0,1)
    f32x4 xaccA = {0.f,0.f,0.f,0.f}, xaccB = {0.f,0.f,0.f,0.f};
    auto compute_x = [&](int s2) {
        xaccA = (f32x4){0.f,0.f,0.f,0.f};
        xaccB = (f32x4){0.f,0.f,0.f,0.f};
        const float* xp = x + ((size_t)arow * T_STEPS + s2) * INPD + kg * 8;
#pragma unroll
        for (int kk = 0; kk < 16; ++kk) {
            f32x4 lo = *(const f32x4*)(xp + kk * 32);
            f32x4 hi = *(const f32x4*)(xp + kk * 32 + 4);
            bf16x8 a;
            a[0]=f2bf(lo[0]); a[1]=f2bf(lo[1]); a[2]=f2bf(lo[2]); a[3]=f2bf(lo[3]);
            a[4]=f2bf(hi[0]); a[5]=f2bf(hi[1]); a[6]=f2bf(hi[2]); a[7]=f2bf(hi[3]);
            xaccA = __builtin_amdgcn_mfma_f32_16x16x32_bf16(a, wfrA[kk], xaccA, 0, 0, 0);
            xaccB = __builtin_amdgcn_mfma_f32_16x16x32_bf16(a, wfrB[kk], xaccB, 0, 0, 0);
        }
    };
    if (wv < 2) compute_x(0);

    f32x4 cst = {0.f, 0.f, 0.f, 0.f};   // c state (wave 0)
    bool dead = false;                   // no-hang bailout (bug path only)

    for (int s = 0; s < T_STEPS; ++s) {
        // ---- consumers: poll tagged h_s, MFMA the h-part ----
        if (wv >= 2) {
            f32x4 accA = {0.f,0.f,0.f,0.f}, accB = {0.f,0.f,0.f,0.f};
            const unsigned* hp = hbuf + (s & 1) * (NBATCH * HID) + arow * HID + kg * 8;
            const unsigned long long tagpat =
                ((unsigned long long)(unsigned)s << 16) |
                ((unsigned long long)(unsigned)s << 48);

#define LSTM_CHUNK(cc)                                                           \
            {                                                                    \
                unsigned long long q[16];                                        \
                int spin = 0;                                                    \
                while (true) {                                                   \
                    unsigned long long m = 0;                                    \
                    _Pragma("unroll")                                            \
                    for (int u = 0; u < 16; ++u) {                               \
                        const int off = ((cc)*4 + (u >> 2)) * 32 + (u & 3) * 2;  \
                        q[u] = __hip_atomic_load(                                \
                            (const unsigned long long*)(hp + off),               \
                            __ATOMIC_RELAXED, __HIP_MEMORY_SCOPE_AGENT);         \
                        m |= (q[u] ^ tagpat) & 0xFFFF0000FFFF0000ULL;            \
                    }                                                            \
                    if (__all(m == 0) || dead) break;                            \
                    if (++spin > (1 << 16)) { dead = true; break; }              \
                }                                                                \
                _Pragma("unroll")                                                \
                for (int t = 0; t < 4; ++t) {                                    \
                    u32x4 wds;                                                   \
                    _Pragma("unroll")                                            \
                    for (int e = 0; e < 4; ++e)                                  \
                        wds[e] = __builtin_amdgcn_perm(                          \
                            (unsigned)(q[t*4+e] >> 32), (unsigned)q[t*4+e],      \
                            0x05040100u);                                        \
                    bf16x8 a = __builtin_bit_cast(bf16x8, wds);                  \
                    accA = __builtin_amdgcn_mfma_f32_16x16x32_bf16(              \
                        a, wfrA[(cc)*4+t], accA, 0, 0, 0);                       \
                    accB = __builtin_amdgcn_mfma_f32_16x16x32_bf16(              \
                        a, wfrB[(cc)*4+t], accB, 0, 0, 0);                       \
                }                                                                \
            }
            LSTM_CHUNK(0) LSTM_CHUNK(1) LSTM_CHUNK(2) LSTM_CHUNK(3)
#undef LSTM_CHUNK

            *(f32x4*)&red[wv - 2][0][lane][0] = accA;
            *(f32x4*)&red[wv - 2][1][lane][0] = accB;
        }
        __syncthreads();   // red ready

        // ---- merge K-halves, gates ----
        f32x4 fvv, ovv;
        if (wv == 1) {
            f32x4 aA = xaccA + *(const f32x4*)&red[1][0][lane][0];
            f32x4 aB = xaccB + *(const f32x4*)&red[1][1][lane][0];
            f32x4 p;
#pragma unroll
            for (int j = 0; j < 4; ++j) {
                float iv = sigmf(aA[j] + biasA);
                float cg = tanhf2(aB[j] + biasB);
                p[j] = iv * cg;
            }
            *(f32x4*)&pbuf[lane][0] = p;
        } else if (wv == 0) {
            f32x4 aA = xaccA + *(const f32x4*)&red[0][0][lane][0];
            f32x4 aB = xaccB + *(const f32x4*)&red[0][1][lane][0];
#pragma unroll
            for (int j = 0; j < 4; ++j) {
                fvv[j] = sigmf(aA[j] + biasA);
                ovv[j] = sigmf(aB[j] + biasB);
            }
        }
        __syncthreads();   // pbuf ready

        // ---- c,h update + tagged publish (no fences, no drains) ----
        if (wv == 0) {
            f32x4 p = *(const f32x4*)&pbuf[lane][0];
            unsigned* hd = hbuf + ((s + 1) & 1) * (NBATCH * HID);
            const unsigned tagw = (unsigned)(s + 1) << 16;
#pragma unroll
            for (int j = 0; j < 4; ++j) {
                float c = fvv[j] * cst[j] + p[j];
                cst[j] = c;
                float h = ovv[j] * tanhf2(c);
                int brow = batch0 + kg * 4 + j;   // D row = 4*kg + j
                if (s == T_STEPS - 1)
                    out[brow * HID + hc] = h;
                else
                    __hip_atomic_store(&hd[brow * HID + hc],
                                       tagw | (unsigned)(unsigned short)f2bf(h),
                                       __ATOMIC_RELAXED, __HIP_MEMORY_SCOPE_AGENT);
            }
        }

        // ---- x-part for step s+1 overlaps consumers' poll+MFMA of s+1 ----
        if (wv < 2 && s + 1 < T_STEPS) compute_x(s + 1);
    }
}

extern "C" void kernel_launch(void* const* d_in, const int* in_sizes, int n_in,
                              void* d_out, int out_size, void* d_ws, size_t ws_size,
                              hipStream_t stream) {
    const float* x  = (const float*)d_in[0];
    const float* Wf = (const float*)d_in[1];
    const float* bf = (const float*)d_in[2];
    const float* Wi = (const float*)d_in[3];
    const float* bi = (const float*)d_in[4];
    const float* Wo = (const float*)d_in[5];
    const float* bo = (const float*)d_in[6];
    const float* Wc = (const float*)d_in[7];
    const float* bc = (const float*)d_in[8];

    char*     ws    = (char*)d_ws;
    short*    wperm = (short*)(ws + WS_W_OFF);
    unsigned* hbuf  = (unsigned*)(ws + WS_H_OFF);

    prep_zero<<<dim3(128),  dim3(256), 0, stream>>>(hbuf);
    prep_w   <<<dim3(2048), dim3(256), 0, stream>>>(Wf, Wi, Wo, Wc, wperm);
    lstm_rec <<<dim3(NCL * WPC), dim3(256), 0, stream>>>(
        x, bf, bi, bo, bc, wperm, hbuf, (float*)d_out);
}

// Round 4
// 3521.375 us; speedup vs baseline: 2.1395x; 1.1390x over previous
//
#include <hip/hip_runtime.h>
#include <hip/hip_bf16.h>

// LSTM: B=64, T=512, I=512, H=512. Output = final h [64,512] fp32.
//
// Round 4 architecture:
//   1) x-part hoisted out of the recurrence: xact[t][b][2048] = x @ W_x + (bias
//      added later), computed by a dedicated MFMA GEMM into ws (bf16, 134MB).
//   2) Recurrence: 4 clusters x 32 WGs x 256thr. WG (cl,w) = batches
//      [16cl,16cl+16), h-cols [16w,16w+16). Wave g owns gate g (f,i,o,C):
//      W_h slice = 16 frags = 64 VGPR (register-resident; round 3's 128-VGPR
//      slice spilled at VGPR_Count=136 -> halved per-wave footprint).
//   3) h fan-in dedup: wave g polls only K-quarter g of tagged h (16 x 8B
//      agent-atomic loads), packs tags out, ds_writes A-frags in frag-order;
//      one sync; every wave ds_read_b128's all 16 A-frags. No red-merge.
//   4) Tag-in-word sync (round-3 proven): h word = (step<<16)|bf16(h),
//      double-buffered; prep kernel zeroes both buffers each call.

#define T_STEPS 512
#define NBATCH  64
#define HID     512
#define NCL     4
#define WPC     32

typedef __attribute__((ext_vector_type(8))) short bf16x8;
typedef __attribute__((ext_vector_type(4))) float f32x4;
typedef __attribute__((ext_vector_type(4))) unsigned u32x4;

// ws layout (bytes)
#define WS_WHF  0                        // whfrag bf16, frag-order: 2MB
#define WS_WXT  (4u<<20)                 // wxT bf16 [2048][512]: 2MB
#define WS_HB   (8u<<20)                 // hbuf [2][64][512] tagged u32: 256KB
#define WS_XBF  (16u<<20)                // xbf bf16 [32768][512]: 32MB
#define WS_XACT (48u<<20)                // xact bf16 [512][64][2048]: 128MB
#define WS_NEED ((size_t)(48u<<20) + ((size_t)T_STEPS*NBATCH*2048*2))

__device__ __forceinline__ short f2bf(float f) {
    unsigned u = __float_as_uint(f);
    unsigned r = u + 0x7fffu + ((u >> 16) & 1u);   // RNE
    return (short)(r >> 16);
}
__device__ __forceinline__ float sigmf(float x) { return 1.f / (1.f + __expf(-x)); }
__device__ __forceinline__ float tanhf2(float x) {
    float a = fabsf(x);
    float e = __expf(-2.f * a);
    float r = (1.f - e) / (1.f + e);
    return x < 0.f ? -r : r;
}

// ---- prep: zero both tagged h buffers (tag 0 matches only s=0, legit h0=0) --
__global__ void prep_zero(unsigned* hbuf) {
    hbuf[blockIdx.x * 256 + threadIdx.x] = 0u;     // 256 blocks -> 65536 words
}

// ---- prep: x fp32 -> bf16 [M=32768][K=512] (flat copy of [B][T][I]) --------
__global__ void prep_xbf(const float* __restrict__ x, short* __restrict__ xbf) {
    size_t i8 = ((size_t)blockIdx.x * 256 + threadIdx.x) * 8;   // 8192 blocks
    f32x4 lo = *(const f32x4*)(x + i8);
    f32x4 hi = *(const f32x4*)(x + i8 + 4);
    bf16x8 v;
    v[0]=f2bf(lo[0]); v[1]=f2bf(lo[1]); v[2]=f2bf(lo[2]); v[3]=f2bf(lo[3]);
    v[4]=f2bf(hi[0]); v[5]=f2bf(hi[1]); v[6]=f2bf(hi[2]); v[7]=f2bf(hi[3]);
    *(bf16x8*)(xbf + i8) = v;
}

// ---- prep: wxT[n][k] = W_g[k][h], n = g*512+h, k in [0,512) (x-part rows) --
__global__ void prep_wx(const float* __restrict__ Wf, const float* __restrict__ Wi,
                        const float* __restrict__ Wo, const float* __restrict__ Wc,
                        short* __restrict__ wxT) {
    int gid = blockIdx.x * 256 + threadIdx.x;      // 512 blocks: 2048 n x 64 k8
    int n = gid >> 6, k0 = (gid & 63) * 8;
    int g = n >> 9, h = n & 511;
    const float* Wg = (g == 0) ? Wf : (g == 1) ? Wi : (g == 2) ? Wo : Wc;
    bf16x8 v;
#pragma unroll
    for (int e = 0; e < 8; ++e) v[e] = f2bf(Wg[(k0 + e) * 512 + h]);
    *(bf16x8*)(wxT + (size_t)n * 512 + k0) = v;
}

// ---- prep: whfrag in fragment order; value = W_g[512 + kk*32 + (l>>4)*8 + e]
//      [16w + (l&15)]  (h-part rows 512..1023) ------------------------------
__global__ void prep_wh(const float* __restrict__ Wf, const float* __restrict__ Wi,
                        const float* __restrict__ Wo, const float* __restrict__ Wc,
                        short* __restrict__ whfrag) {
    int gid = blockIdx.x * 256 + threadIdx.x;      // 512 blocks: 32w*4g*16kk*64l
    int l = gid & 63, kk = (gid >> 6) & 15, g = (gid >> 10) & 3, w = gid >> 12;
    const float* Wg = (g == 0) ? Wf : (g == 1) ? Wi : (g == 2) ? Wo : Wc;
    int krow = 512 + kk * 32 + (l >> 4) * 8;
    int col  = 16 * w + (l & 15);
    bf16x8 v;
#pragma unroll
    for (int e = 0; e < 8; ++e) v[e] = f2bf(Wg[(krow + e) * 512 + col]);
    *(bf16x8*)(whfrag + (size_t)gid * 8) = v;
}

// ---- xact GEMM: [M=32768,K=512] x [K=512,N=2048] -> xact[t][b][n] bf16 ------
__launch_bounds__(256, 1)
__global__ void xgemm(const short* __restrict__ xbf, const short* __restrict__ wxT,
                      short* __restrict__ xact) {
    const int l  = threadIdx.x & 63;
    const int wv = threadIdx.x >> 6;
    const int m0 = blockIdx.y * 128 + (wv >> 1) * 64;
    const int n0 = blockIdx.x * 128 + (wv & 1) * 64;

    f32x4 acc[4][4] = {};
    const short* ap = xbf + (size_t)(m0 + (l & 15)) * 512 + (l >> 4) * 8;
    const short* bp = wxT + (size_t)(n0 + (l & 15)) * 512 + (l >> 4) * 8;

    for (int kk = 0; kk < 16; ++kk) {
        bf16x8 a[4], b[4];
#pragma unroll
        for (int r = 0; r < 4; ++r) a[r] = *(const bf16x8*)(ap + r * 8192 + kk * 32);
#pragma unroll
        for (int q = 0; q < 4; ++q) b[q] = *(const bf16x8*)(bp + q * 8192 + kk * 32);
#pragma unroll
        for (int r = 0; r < 4; ++r)
#pragma unroll
            for (int q = 0; q < 4; ++q)
                acc[r][q] = __builtin_amdgcn_mfma_f32_16x16x32_bf16(a[r], b[q], acc[r][q], 0, 0, 0);
    }
#pragma unroll
    for (int r = 0; r < 4; ++r)
#pragma unroll
        for (int q = 0; q < 4; ++q)
#pragma unroll
            for (int j = 0; j < 4; ++j) {
                int m = m0 + r * 16 + (l >> 4) * 4 + j;
                int b_ = m >> 9, t = m & 511;
                int n = n0 + q * 16 + (l & 15);
                xact[((size_t)t * 64 + b_) * 2048 + n] = f2bf(acc[r][q][j]);
            }
}

// ---- recurrence -------------------------------------------------------------
__launch_bounds__(256, 1)
__global__ void lstm_rec(const short* __restrict__ xact,
                         const float* __restrict__ bfp, const float* __restrict__ bip,
                         const float* __restrict__ bop, const float* __restrict__ bcp,
                         const short* __restrict__ whfrag,
                         unsigned* __restrict__ hbuf,     // [2][64][512] tagged
                         float* __restrict__ out)         // [64][512] fp32
{
    const int tid = threadIdx.x;
    const int g   = tid >> 6;          // wave = gate (0=f,1=i,2=o,3=C)
    const int l   = tid & 63;
    const int bid = blockIdx.x;
    const int cl  = bid & (NCL - 1);
    const int w   = bid >> 2;
    const int batch0 = cl * 16;

    // W_h fragments: 16 x bf16x8 = 64 VGPR, register-resident
    bf16x8 wfr[16];
    {
        const short* wp = whfrag + (((size_t)(w * 4 + g) * 16) * 64 + l) * 8;
#pragma unroll
        for (int kk = 0; kk < 16; ++kk)
            wfr[kk] = *(const bf16x8*)(wp + (size_t)kk * 512);
#pragma unroll
        for (int kk = 0; kk < 16; ++kk)
            asm volatile("" : "+v"(wfr[kk]));
    }

    const int hcol = 16 * w + (l & 15);
    const float* bptr = (g == 0) ? bfp : (g == 1) ? bip : (g == 2) ? bop : bcp;
    const float bias = bptr[hcol];
    const size_t xn = (size_t)g * 512 + hcol;

    __shared__ short alds[16][64][8];   // A-frags, frag-order (16KB)
    __shared__ float gbuf[3][64][4];    // activated f,i,o exchange (3KB)

    const int rowA = batch0 + (l & 15); // poll row (A-frag row = batch)
    const int rowD = batch0 + (l >> 4) * 4;   // D-frag row base (+j)

    f32x4 c = {0.f, 0.f, 0.f, 0.f};     // c state (wave 3)
    bool dead = false;

    for (int s = 0; s < T_STEPS; ++s) {
        // xact loads issued early, consumed after MFMA
        unsigned short xw[4];
#pragma unroll
        for (int j = 0; j < 4; ++j)
            xw[j] = *((const unsigned short*)xact + ((size_t)s * 64 + rowD + j) * 2048 + xn);

        // ---- poll K-quarter g of h_s (16 x 8B tagged agent loads) ----
        unsigned long long q[16];
        {
            const unsigned* hp = hbuf + (s & 1) * (NBATCH * HID)
                               + rowA * HID + g * 128 + (l >> 4) * 8;
            const unsigned long long tagpat =
                ((unsigned long long)(unsigned)s << 16) |
                ((unsigned long long)(unsigned)s << 48);
            int spin = 0;
            while (true) {
                unsigned long long m = 0;
#pragma unroll
                for (int u = 0; u < 16; ++u) {   // u = sub*4+p: cols sub*32+p*2
                    q[u] = __hip_atomic_load(
                        (const unsigned long long*)(hp + (u >> 2) * 32 + (u & 3) * 2),
                        __ATOMIC_RELAXED, __HIP_MEMORY_SCOPE_AGENT);
                    m |= (q[u] ^ tagpat) & 0xFFFF0000FFFF0000ULL;
                }
                if (__all(m == 0) || dead) break;
                if (++spin > (1 << 17)) dead = true;
            }
        }
        // pack (strip tags) + ds_write frag-order
#pragma unroll
        for (int sub = 0; sub < 4; ++sub) {
            u32x4 wd;
#pragma unroll
            for (int p = 0; p < 4; ++p)
                wd[p] = __builtin_amdgcn_perm(
                    (unsigned)(q[sub * 4 + p] >> 32), (unsigned)q[sub * 4 + p],
                    0x05040100u);
            *(u32x4*)&alds[g * 4 + sub][l][0] = wd;
        }
        __syncthreads();   // A-frags ready

        // ---- 16 MFMA over K=512, 2 chains ----
        f32x4 acc0 = {0.f,0.f,0.f,0.f}, acc1 = {0.f,0.f,0.f,0.f};
#pragma unroll
        for (int kk = 0; kk < 16; kk += 2) {
            bf16x8 a0 = *(const bf16x8*)&alds[kk][l][0];
            bf16x8 a1 = *(const bf16x8*)&alds[kk + 1][l][0];
            acc0 = __builtin_amdgcn_mfma_f32_16x16x32_bf16(a0, wfr[kk],     acc0, 0, 0, 0);
            acc1 = __builtin_amdgcn_mfma_f32_16x16x32_bf16(a1, wfr[kk + 1], acc1, 0, 0, 0);
        }
        f32x4 pre = acc0 + acc1;

        // ---- activation ----
        f32x4 act;
#pragma unroll
        for (int j = 0; j < 4; ++j) {
            float v = pre[j] + __uint_as_float((unsigned)xw[j] << 16) + bias;
            act[j] = (g == 3) ? tanhf2(v) : sigmf(v);
        }
        if (g < 3) *(f32x4*)&gbuf[g][l][0] = act;
        __syncthreads();   // gates ready

        // ---- c,h update + tagged publish (wave 3) ----
        if (g == 3) {
            f32x4 fv = *(const f32x4*)&gbuf[0][l][0];
            f32x4 iv = *(const f32x4*)&gbuf[1][l][0];
            f32x4 ov = *(const f32x4*)&gbuf[2][l][0];
            unsigned* hd = hbuf + ((s + 1) & 1) * (NBATCH * HID);
            const unsigned tagw = (unsigned)(s + 1) << 16;
#pragma unroll
            for (int j = 0; j < 4; ++j) {
                c[j] = fv[j] * c[j] + iv[j] * act[j];
                float h = ov[j] * tanhf2(c[j]);
                if (s == T_STEPS - 1)
                    out[(rowD + j) * HID + hcol] = h;
                else
                    __hip_atomic_store(&hd[(rowD + j) * HID + hcol],
                                       tagw | (unsigned)(unsigned short)f2bf(h),
                                       __ATOMIC_RELAXED, __HIP_MEMORY_SCOPE_AGENT);
            }
        }
    }
}

extern "C" void kernel_launch(void* const* d_in, const int* in_sizes, int n_in,
                              void* d_out, int out_size, void* d_ws, size_t ws_size,
                              hipStream_t stream) {
    const float* x  = (const float*)d_in[0];
    const float* Wf = (const float*)d_in[1];
    const float* bf = (const float*)d_in[2];
    const float* Wi = (const float*)d_in[3];
    const float* bi = (const float*)d_in[4];
    const float* Wo = (const float*)d_in[5];
    const float* bo = (const float*)d_in[6];
    const float* Wc = (const float*)d_in[7];
    const float* bc = (const float*)d_in[8];

    if (ws_size < WS_NEED) return;   // loud failure: out stays poison

    char*     ws     = (char*)d_ws;
    short*    whfrag = (short*)(ws + WS_WHF);
    short*    wxT    = (short*)(ws + WS_WXT);
    unsigned* hbuf   = (unsigned*)(ws + WS_HB);
    short*    xbf    = (short*)(ws + WS_XBF);
    short*    xact   = (short*)(ws + WS_XACT);

    prep_zero<<<dim3(256),  dim3(256), 0, stream>>>(hbuf);
    prep_xbf <<<dim3(8192), dim3(256), 0, stream>>>(x, xbf);
    prep_wx  <<<dim3(512),  dim3(256), 0, stream>>>(Wf, Wi, Wo, Wc, wxT);
    prep_wh  <<<dim3(512),  dim3(256), 0, stream>>>(Wf, Wi, Wo, Wc, whfrag);
    xgemm    <<<dim3(16, 256), dim3(256), 0, stream>>>(xbf, wxT, xact);
    lstm_rec <<<dim3(NCL * WPC), dim3(256), 0, stream>>>(
        xact, bf, bi, bo, bc, whfrag, hbuf, (float*)d_out);
}

// Round 5
// 3339.518 us; speedup vs baseline: 2.2560x; 1.0545x over previous
//
#include <hip/hip_runtime.h>
#include <hip/hip_bf16.h>

// LSTM: B=64, T=512, I=512, H=512. Output = final h [64,512] fp32.
//
// Round 5 architecture:
//   1) xact[t][b][2048] = x @ W_x precomputed by MFMA GEMM (round-4 proven).
//   2) Recurrence: 4 clusters x 32 WGs x 256thr. WG (cl,w) = batches
//      [16cl,16cl+16), hcols [16w,16w+16). NEW: wave v owns hcols
//      [16w+4v, 16w+4v+4) x ALL FOUR GATES (gate-major packed B-tile:
//      col = gate*4 + hcl). Every wave is symmetric:
//        poll K-quarter v -> LDS A-frag dedup -> 1 barrier -> 16 MFMA ->
//        unified activation -> in-wave XOR butterfly (shfl_xor 4,8) gathers
//        f,i,o,C -> per-lane c-update -> each lane publishes j == its gate.
//      No second barrier, no gate LDS exchange, no wave-3 serial tail.
//   3) alds double-buffered (parity s&1) => single __syncthreads per step.
//   4) xact prefetched one step ahead (HBM latency off the critical path).
//   5) Activations via v_exp_f32 + v_rcp_f32: act = A*rcp(1+exp2(K*v))+C,
//      (A,K,C) per-lane constants: sigmoid (1,-log2e,0), tanh (2,-2log2e,-1).
//   6) Tag-in-word sync (round-3 proven): h word = (step<<16)|bf16(h),
//      double-buffered, relaxed agent atomics, no fences.

#define T_STEPS 512
#define NBATCH  64
#define HID     512
#define NCL     4
#define WPC     32

typedef __attribute__((ext_vector_type(8))) short bf16x8;
typedef __attribute__((ext_vector_type(4))) float f32x4;
typedef __attribute__((ext_vector_type(4))) unsigned u32x4;

// ws layout (bytes)
#define WS_WHF  0                        // whfrag bf16, frag-order: 2MB
#define WS_WXT  (4u<<20)                 // wxT bf16 [2048][512]: 2MB
#define WS_HB   (8u<<20)                 // hbuf [2][64][512] tagged u32: 256KB
#define WS_XBF  (16u<<20)                // xbf bf16 [32768][512]: 32MB
#define WS_XACT (48u<<20)                // xact bf16 [512][64][2048]: 128MB
#define WS_NEED ((size_t)(48u<<20) + ((size_t)T_STEPS*NBATCH*2048*2))

__device__ __forceinline__ short f2bf(float f) {
    unsigned u = __float_as_uint(f);
    unsigned r = u + 0x7fffu + ((u >> 16) & 1u);   // RNE
    return (short)(r >> 16);
}

__global__ void prep_zero(unsigned* hbuf) {
    hbuf[blockIdx.x * 256 + threadIdx.x] = 0u;     // 256 blocks -> 65536 words
}

__global__ void prep_xbf(const float* __restrict__ x, short* __restrict__ xbf) {
    size_t i8 = ((size_t)blockIdx.x * 256 + threadIdx.x) * 8;   // 8192 blocks
    f32x4 lo = *(const f32x4*)(x + i8);
    f32x4 hi = *(const f32x4*)(x + i8 + 4);
    bf16x8 v;
    v[0]=f2bf(lo[0]); v[1]=f2bf(lo[1]); v[2]=f2bf(lo[2]); v[3]=f2bf(lo[3]);
    v[4]=f2bf(hi[0]); v[5]=f2bf(hi[1]); v[6]=f2bf(hi[2]); v[7]=f2bf(hi[3]);
    *(bf16x8*)(xbf + i8) = v;
}

// wxT[n][k] = W_g[k][h], n = g*512+h, k in [0,512)  (x-part rows of W)
__global__ void prep_wx(const float* __restrict__ Wf, const float* __restrict__ Wi,
                        const float* __restrict__ Wo, const float* __restrict__ Wc,
                        short* __restrict__ wxT) {
    int gid = blockIdx.x * 256 + threadIdx.x;      // 512 blocks
    int n = gid >> 6, k0 = (gid & 63) * 8;
    int g = n >> 9, h = n & 511;
    const float* Wg = (g == 0) ? Wf : (g == 1) ? Wi : (g == 2) ? Wo : Wc;
    bf16x8 v;
#pragma unroll
    for (int e = 0; e < 8; ++e) v[e] = f2bf(Wg[(k0 + e) * 512 + h]);
    *(bf16x8*)(wxT + (size_t)n * 512 + k0) = v;
}

// whfrag, frag-order, GATE-MAJOR packed cols: B-tile col (l&15) = gate*4+hcl,
// hcol = 16w + 4v + hcl; value = W_gate[512 + kk*32 + (l>>4)*8 + e][hcol]
__global__ void prep_wh(const float* __restrict__ Wf, const float* __restrict__ Wi,
                        const float* __restrict__ Wo, const float* __restrict__ Wc,
                        short* __restrict__ whfrag) {
    int gid = blockIdx.x * 256 + threadIdx.x;      // 512 blocks: 32w*4v*16kk*64l
    int l = gid & 63, kk = (gid >> 6) & 15, v = (gid >> 10) & 3, w = gid >> 12;
    int c16 = l & 15, gate = c16 >> 2, hcl = c16 & 3;
    int hcol = 16 * w + 4 * v + hcl;
    const float* Wg = (gate == 0) ? Wf : (gate == 1) ? Wi : (gate == 2) ? Wo : Wc;
    int krow = 512 + kk * 32 + (l >> 4) * 8;
    bf16x8 vv;
#pragma unroll
    for (int e = 0; e < 8; ++e) vv[e] = f2bf(Wg[(krow + e) * 512 + hcol]);
    *(bf16x8*)(whfrag + (size_t)gid * 8) = vv;
}

// xact GEMM: [M=32768,K=512] x [K=512,N=2048] -> xact[t][b][n] bf16
__launch_bounds__(256, 1)
__global__ void xgemm(const short* __restrict__ xbf, const short* __restrict__ wxT,
                      short* __restrict__ xact) {
    const int l  = threadIdx.x & 63;
    const int wv = threadIdx.x >> 6;
    const int m0 = blockIdx.y * 128 + (wv >> 1) * 64;
    const int n0 = blockIdx.x * 128 + (wv & 1) * 64;

    f32x4 acc[4][4] = {};
    const short* ap = xbf + (size_t)(m0 + (l & 15)) * 512 + (l >> 4) * 8;
    const short* bp = wxT + (size_t)(n0 + (l & 15)) * 512 + (l >> 4) * 8;

    for (int kk = 0; kk < 16; ++kk) {
        bf16x8 a[4], b[4];
#pragma unroll
        for (int r = 0; r < 4; ++r) a[r] = *(const bf16x8*)(ap + r * 8192 + kk * 32);
#pragma unroll
        for (int q = 0; q < 4; ++q) b[q] = *(const bf16x8*)(bp + q * 8192 + kk * 32);
#pragma unroll
        for (int r = 0; r < 4; ++r)
#pragma unroll
            for (int q = 0; q < 4; ++q)
                acc[r][q] = __builtin_amdgcn_mfma_f32_16x16x32_bf16(a[r], b[q], acc[r][q], 0, 0, 0);
    }
#pragma unroll
    for (int r = 0; r < 4; ++r)
#pragma unroll
        for (int q = 0; q < 4; ++q)
#pragma unroll
            for (int j = 0; j < 4; ++j) {
                int m = m0 + r * 16 + (l >> 4) * 4 + j;
                int b_ = m >> 9, t = m & 511;
                int n = n0 + q * 16 + (l & 15);
                xact[((size_t)t * 64 + b_) * 2048 + n] = f2bf(acc[r][q][j]);
            }
}

__device__ __forceinline__ f32x4 shfx4(f32x4 v, int mask) {
    f32x4 r;
#pragma unroll
    for (int e = 0; e < 4; ++e) r[e] = __shfl_xor(v[e], mask, 64);
    return r;
}

// ---- recurrence -------------------------------------------------------------
__launch_bounds__(256, 1)
__global__ void lstm_rec(const short* __restrict__ xact,
                         const float* __restrict__ bfp, const float* __restrict__ bip,
                         const float* __restrict__ bop, const float* __restrict__ bcp,
                         const short* __restrict__ whfrag,
                         unsigned* __restrict__ hbuf,     // [2][64][512] tagged
                         float* __restrict__ out)         // [64][512] fp32
{
    const int tid = threadIdx.x;
    const int v   = tid >> 6;          // wave = hcol sub-slice (4 cols x 4 gates)
    const int l   = tid & 63;
    const int bid = blockIdx.x;
    const int cl  = bid & (NCL - 1);
    const int w   = bid >> 2;
    const int batch0 = cl * 16;

    // W_h fragments: 16 x bf16x8 = 64 VGPR, register-resident
    bf16x8 wfr[16];
    {
        const short* wp = whfrag + (((size_t)(w * 4 + v) * 16) * 64 + l) * 8;
#pragma unroll
        for (int kk = 0; kk < 16; ++kk)
            wfr[kk] = *(const bf16x8*)(wp + (size_t)kk * 512);
#pragma unroll
        for (int kk = 0; kk < 16; ++kk)
            asm volatile("" : "+v"(wfr[kk]));
    }

    const int g    = (l >> 2) & 3;              // this lane's gate
    const int hcol = 16 * w + 4 * v + (l & 3);  // this lane's h column
    const float* bp2 = (g == 0) ? bfp : (g == 1) ? bip : (g == 2) ? bop : bcp;
    const float bias = bp2[hcol];
    // unified activation constants: act = A*rcp(1+exp2(K*x)) + C
    const float Aa = (g == 3) ? 2.f : 1.f;
    const float Kk = (g == 3) ? -2.885390082f : -1.442695041f;
    const float Cc = (g == 3) ? -1.f : 0.f;

    __shared__ short alds[2][16][64][8];   // A-frags, double-buffered (32KB)

    const int rowA  = batch0 + (l & 15);        // poll row (A-frag row = batch)
    const int rowD0 = batch0 + (l >> 4) * 4;    // D-frag row base (+j)
    const unsigned short* xa = (const unsigned short*)xact;

    f32x4 c = {0.f, 0.f, 0.f, 0.f};
    bool dead = false;

    // prefetch xact for s=0
    unsigned short xw[4];
#pragma unroll
    for (int j = 0; j < 4; ++j)
        xw[j] = xa[((size_t)0 * 64 + rowD0 + j) * 2048 + g * 512 + hcol];

    for (int s = 0; s < T_STEPS; ++s) {
        // ---- poll K-quarter v of h_s (16 x 8B tagged agent loads) ----
        unsigned long long q[16];
        {
            const unsigned* hp = hbuf + (s & 1) * (NBATCH * HID)
                               + rowA * HID + v * 128 + (l >> 4) * 8;
            const unsigned long long tagpat =
                ((unsigned long long)(unsigned)s << 16) |
                ((unsigned long long)(unsigned)s << 48);
            int spin = 0;
            while (true) {
                unsigned long long m = 0;
#pragma unroll
                for (int u = 0; u < 16; ++u) {
                    q[u] = __hip_atomic_load(
                        (const unsigned long long*)(hp + (u >> 2) * 32 + (u & 3) * 2),
                        __ATOMIC_RELAXED, __HIP_MEMORY_SCOPE_AGENT);
                    m |= (q[u] ^ tagpat) & 0xFFFF0000FFFF0000ULL;
                }
                if (__all(m == 0) || dead) break;
                if (++spin > (1 << 17)) dead = true;
            }
        }

        // ---- prefetch xact for s+1 (consumed next iteration) ----
        unsigned short xwn[4];
        if (s + 1 < T_STEPS) {
#pragma unroll
            for (int j = 0; j < 4; ++j)
                xwn[j] = xa[((size_t)(s + 1) * 64 + rowD0 + j) * 2048 + g * 512 + hcol];
        }

        // ---- pack (strip tags) + ds_write frag-order ----
#pragma unroll
        for (int sub = 0; sub < 4; ++sub) {
            u32x4 wd;
#pragma unroll
            for (int p = 0; p < 4; ++p)
                wd[p] = __builtin_amdgcn_perm(
                    (unsigned)(q[sub * 4 + p] >> 32), (unsigned)q[sub * 4 + p],
                    0x05040100u);
            *(u32x4*)&alds[s & 1][v * 4 + sub][l][0] = wd;
        }
        __syncthreads();   // A-frags ready (single barrier per step)

        // ---- 16 MFMA over K=512, 2 chains ----
        f32x4 acc0 = {0.f,0.f,0.f,0.f}, acc1 = {0.f,0.f,0.f,0.f};
#pragma unroll
        for (int kk = 0; kk < 16; kk += 2) {
            bf16x8 a0 = *(const bf16x8*)&alds[s & 1][kk][l][0];
            bf16x8 a1 = *(const bf16x8*)&alds[s & 1][kk + 1][l][0];
            acc0 = __builtin_amdgcn_mfma_f32_16x16x32_bf16(a0, wfr[kk],     acc0, 0, 0, 0);
            acc1 = __builtin_amdgcn_mfma_f32_16x16x32_bf16(a1, wfr[kk + 1], acc1, 0, 0, 0);
        }
        f32x4 pre = acc0 + acc1;

        // ---- unified activation (this lane's gate, 4 rows) ----
        f32x4 own;
#pragma unroll
        for (int j = 0; j < 4; ++j) {
            float vv = pre[j] + __uint_as_float((unsigned)xw[j] << 16) + bias;
            float e  = __builtin_amdgcn_exp2f(Kk * vv);
            own[j]   = __builtin_fmaf(Aa, __builtin_amdgcn_rcpf(1.f + e), Cc);
        }
#pragma unroll
        for (int j = 0; j < 4; ++j) xw[j] = xwn[j];

        // ---- in-wave XOR butterfly: gather f,i,o,C (lanes l^4, l^8, l^12) ----
        f32x4 r1 = shfx4(own, 4);
        f32x4 r2 = shfx4(own, 8);
        f32x4 r3 = shfx4(r1, 8);
        f32x4 fv = (g == 0) ? own : (g == 1) ? r1 : (g == 2) ? r2 : r3;
        f32x4 iv = (g == 0) ? r1 : (g == 1) ? own : (g == 2) ? r3 : r2;
        f32x4 ov = (g == 0) ? r2 : (g == 1) ? r3 : (g == 2) ? own : r1;
        f32x4 Cv = (g == 0) ? r3 : (g == 1) ? r2 : (g == 2) ? r1 : own;

        // ---- c update (4x lane-redundant, deterministic) ----
        c = fv * c + iv * Cv;

        // ---- publish: this lane stores row j == its gate id ----
        float cg  = (g == 0) ? c[0] : (g == 1) ? c[1] : (g == 2) ? c[2] : c[3];
        float og  = (g == 0) ? ov[0] : (g == 1) ? ov[1] : (g == 2) ? ov[2] : ov[3];
        float e2  = __builtin_amdgcn_exp2f(-2.885390082f * cg);
        float th  = __builtin_fmaf(2.f, __builtin_amdgcn_rcpf(1.f + e2), -1.f);
        float h   = og * th;
        int   row = rowD0 + g;
        if (s == T_STEPS - 1) {
            out[row * HID + hcol] = h;
        } else {
            unsigned* hd = hbuf + ((s + 1) & 1) * (NBATCH * HID);
            __hip_atomic_store(&hd[row * HID + hcol],
                               ((unsigned)(s + 1) << 16) |
                               (unsigned)(unsigned short)f2bf(h),
                               __ATOMIC_RELAXED, __HIP_MEMORY_SCOPE_AGENT);
        }
    }
}

extern "C" void kernel_launch(void* const* d_in, const int* in_sizes, int n_in,
                              void* d_out, int out_size, void* d_ws, size_t ws_size,
                              hipStream_t stream) {
    const float* x  = (const float*)d_in[0];
    const float* Wf = (const float*)d_in[1];
    const float* bf = (const float*)d_in[2];
    const float* Wi = (const float*)d_in[3];
    const float* bi = (const float*)d_in[4];
    const float* Wo = (const float*)d_in[5];
    const float* bo = (const float*)d_in[6];
    const float* Wc = (const float*)d_in[7];
    const float* bc = (const float*)d_in[8];

    if (ws_size < WS_NEED) return;   // loud failure: out stays poison

    char*     ws     = (char*)d_ws;
    short*    whfrag = (short*)(ws + WS_WHF);
    short*    wxT    = (short*)(ws + WS_WXT);
    unsigned* hbuf   = (unsigned*)(ws + WS_HB);
    short*    xbf    = (short*)(ws + WS_XBF);
    short*    xact   = (short*)(ws + WS_XACT);

    prep_zero<<<dim3(256),  dim3(256), 0, stream>>>(hbuf);
    prep_xbf <<<dim3(8192), dim3(256), 0, stream>>>(x, xbf);
    prep_wx  <<<dim3(512),  dim3(256), 0, stream>>>(Wf, Wi, Wo, Wc, wxT);
    prep_wh  <<<dim3(512),  dim3(256), 0, stream>>>(Wf, Wi, Wo, Wc, whfrag);
    xgemm    <<<dim3(16, 256), dim3(256), 0, stream>>>(xbf, wxT, xact);
    lstm_rec <<<dim3(NCL * WPC), dim3(256), 0, stream>>>(
        xact, bf, bi, bo, bc, whfrag, hbuf, (float*)d_out);
}

// Round 6
// 2342.831 us; speedup vs baseline: 3.2157x; 1.4254x over previous
//
#include <hip/hip_runtime.h>
#include <hip/hip_bf16.h>

// LSTM: B=64, T=512, I=512, H=512. Output = final h [64,512] fp32.
//
// Round 6 = round 5 + batched poll loads.
//   Theory: round 3-5's poll body (16 x __hip_atomic_load feeding the tag
//   check) lowers to CHAINED atomic loads -> load, s_waitcnt, xor x16 =
//   16 serial MALL round trips (~4us) per poll iteration. Replaced with ONE
//   inline-asm block: 16 x global_load_dwordx2 sc0 sc1 (pipelined) + a single
//   s_waitcnt vmcnt(0) inside the block (outputs defined only at block
//   retire -> no use-hoisting hazard). Poll iteration ~4us -> ~0.35us.
//   Also: xact prefetch issued BEFORE the poll loop (memory clobber would
//   pin it after), s_sleep(1) backoff after 8 failed spins.
//
//   Carried from round 5: xact = x@W_x precomputed by MFMA GEMM; 4 clusters
//   x 32 WGs; wave v owns hcols [16w+4v,+4) x all 4 gates (gate-major
//   B-tile); symmetric waves; in-wave XOR butterfly gate exchange; 1 barrier
//   per step (double-buffered alds); tag-in-word h sync (word =
//   (step<<16)|bf16(h), double-buffered, relaxed agent atomics, no fences);
//   W_h register-resident (16 frags = 64 VGPR + asm anchors).

#define T_STEPS 512
#define NBATCH  64
#define HID     512
#define NCL     4
#define WPC     32

typedef __attribute__((ext_vector_type(8))) short bf16x8;
typedef __attribute__((ext_vector_type(4))) float f32x4;
typedef __attribute__((ext_vector_type(4))) unsigned u32x4;

// ws layout (bytes)
#define WS_WHF  0                        // whfrag bf16, frag-order: 2MB
#define WS_WXT  (4u<<20)                 // wxT bf16 [2048][512]: 2MB
#define WS_HB   (8u<<20)                 // hbuf [2][64][512] tagged u32: 256KB
#define WS_XBF  (16u<<20)                // xbf bf16 [32768][512]: 32MB
#define WS_XACT (48u<<20)                // xact bf16 [512][64][2048]: 128MB
#define WS_NEED ((size_t)(48u<<20) + ((size_t)T_STEPS*NBATCH*2048*2))

__device__ __forceinline__ short f2bf(float f) {
    unsigned u = __float_as_uint(f);
    unsigned r = u + 0x7fffu + ((u >> 16) & 1u);   // RNE
    return (short)(r >> 16);
}

__global__ void prep_zero(unsigned* hbuf) {
    hbuf[blockIdx.x * 256 + threadIdx.x] = 0u;     // 256 blocks -> 65536 words
}

__global__ void prep_xbf(const float* __restrict__ x, short* __restrict__ xbf) {
    size_t i8 = ((size_t)blockIdx.x * 256 + threadIdx.x) * 8;   // 8192 blocks
    f32x4 lo = *(const f32x4*)(x + i8);
    f32x4 hi = *(const f32x4*)(x + i8 + 4);
    bf16x8 v;
    v[0]=f2bf(lo[0]); v[1]=f2bf(lo[1]); v[2]=f2bf(lo[2]); v[3]=f2bf(lo[3]);
    v[4]=f2bf(hi[0]); v[5]=f2bf(hi[1]); v[6]=f2bf(hi[2]); v[7]=f2bf(hi[3]);
    *(bf16x8*)(xbf + i8) = v;
}

// wxT[n][k] = W_g[k][h], n = g*512+h, k in [0,512)  (x-part rows of W)
__global__ void prep_wx(const float* __restrict__ Wf, const float* __restrict__ Wi,
                        const float* __restrict__ Wo, const float* __restrict__ Wc,
                        short* __restrict__ wxT) {
    int gid = blockIdx.x * 256 + threadIdx.x;      // 512 blocks
    int n = gid >> 6, k0 = (gid & 63) * 8;
    int g = n >> 9, h = n & 511;
    const float* Wg = (g == 0) ? Wf : (g == 1) ? Wi : (g == 2) ? Wo : Wc;
    bf16x8 v;
#pragma unroll
    for (int e = 0; e < 8; ++e) v[e] = f2bf(Wg[(k0 + e) * 512 + h]);
    *(bf16x8*)(wxT + (size_t)n * 512 + k0) = v;
}

// whfrag, frag-order, GATE-MAJOR packed cols: B-tile col (l&15) = gate*4+hcl,
// hcol = 16w + 4v + hcl; value = W_gate[512 + kk*32 + (l>>4)*8 + e][hcol]
__global__ void prep_wh(const float* __restrict__ Wf, const float* __restrict__ Wi,
                        const float* __restrict__ Wo, const float* __restrict__ Wc,
                        short* __restrict__ whfrag) {
    int gid = blockIdx.x * 256 + threadIdx.x;      // 512 blocks: 32w*4v*16kk*64l
    int l = gid & 63, kk = (gid >> 6) & 15, v = (gid >> 10) & 3, w = gid >> 12;
    int c16 = l & 15, gate = c16 >> 2, hcl = c16 & 3;
    int hcol = 16 * w + 4 * v + hcl;
    const float* Wg = (gate == 0) ? Wf : (gate == 1) ? Wi : (gate == 2) ? Wo : Wc;
    int krow = 512 + kk * 32 + (l >> 4) * 8;
    bf16x8 vv;
#pragma unroll
    for (int e = 0; e < 8; ++e) vv[e] = f2bf(Wg[(krow + e) * 512 + hcol]);
    *(bf16x8*)(whfrag + (size_t)gid * 8) = vv;
}

// xact GEMM: [M=32768,K=512] x [K=512,N=2048] -> xact[t][b][n] bf16
__launch_bounds__(256, 1)
__global__ void xgemm(const short* __restrict__ xbf, const short* __restrict__ wxT,
                      short* __restrict__ xact) {
    const int l  = threadIdx.x & 63;
    const int wv = threadIdx.x >> 6;
    const int m0 = blockIdx.y * 128 + (wv >> 1) * 64;
    const int n0 = blockIdx.x * 128 + (wv & 1) * 64;

    f32x4 acc[4][4] = {};
    const short* ap = xbf + (size_t)(m0 + (l & 15)) * 512 + (l >> 4) * 8;
    const short* bp = wxT + (size_t)(n0 + (l & 15)) * 512 + (l >> 4) * 8;

    for (int kk = 0; kk < 16; ++kk) {
        bf16x8 a[4], b[4];
#pragma unroll
        for (int r = 0; r < 4; ++r) a[r] = *(const bf16x8*)(ap + r * 8192 + kk * 32);
#pragma unroll
        for (int q = 0; q < 4; ++q) b[q] = *(const bf16x8*)(bp + q * 8192 + kk * 32);
#pragma unroll
        for (int r = 0; r < 4; ++r)
#pragma unroll
            for (int q = 0; q < 4; ++q)
                acc[r][q] = __builtin_amdgcn_mfma_f32_16x16x32_bf16(a[r], b[q], acc[r][q], 0, 0, 0);
    }
#pragma unroll
    for (int r = 0; r < 4; ++r)
#pragma unroll
        for (int q = 0; q < 4; ++q)
#pragma unroll
            for (int j = 0; j < 4; ++j) {
                int m = m0 + r * 16 + (l >> 4) * 4 + j;
                int b_ = m >> 9, t = m & 511;
                int n = n0 + q * 16 + (l & 15);
                xact[((size_t)t * 64 + b_) * 2048 + n] = f2bf(acc[r][q][j]);
            }
}

__device__ __forceinline__ f32x4 shfx4(f32x4 v, int mask) {
    f32x4 r;
#pragma unroll
    for (int e = 0; e < 4; ++e) r[e] = __shfl_xor(v[e], mask, 64);
    return r;
}

// ---- recurrence -------------------------------------------------------------
__launch_bounds__(256, 1)
__global__ void lstm_rec(const short* __restrict__ xact,
                         const float* __restrict__ bfp, const float* __restrict__ bip,
                         const float* __restrict__ bop, const float* __restrict__ bcp,
                         const short* __restrict__ whfrag,
                         unsigned* __restrict__ hbuf,     // [2][64][512] tagged
                         float* __restrict__ out)         // [64][512] fp32
{
    const int tid = threadIdx.x;
    const int v   = tid >> 6;          // wave = hcol sub-slice (4 cols x 4 gates)
    const int l   = tid & 63;
    const int bid = blockIdx.x;
    const int cl  = bid & (NCL - 1);
    const int w   = bid >> 2;
    const int batch0 = cl * 16;

    // W_h fragments: 16 x bf16x8 = 64 VGPR, register-resident
    bf16x8 wfr[16];
    {
        const short* wp = whfrag + (((size_t)(w * 4 + v) * 16) * 64 + l) * 8;
#pragma unroll
        for (int kk = 0; kk < 16; ++kk)
            wfr[kk] = *(const bf16x8*)(wp + (size_t)kk * 512);
#pragma unroll
        for (int kk = 0; kk < 16; ++kk)
            asm volatile("" : "+v"(wfr[kk]));
    }

    const int g    = (l >> 2) & 3;              // this lane's gate
    const int hcol = 16 * w + 4 * v + (l & 3);  // this lane's h column
    const float* bp2 = (g == 0) ? bfp : (g == 1) ? bip : (g == 2) ? bop : bcp;
    const float bias = bp2[hcol];
    // unified activation constants: act = A*rcp(1+exp2(K*x)) + C
    const float Aa = (g == 3) ? 2.f : 1.f;
    const float Kk = (g == 3) ? -2.885390082f : -1.442695041f;
    const float Cc = (g == 3) ? -1.f : 0.f;

    __shared__ short alds[2][16][64][8];   // A-frags, double-buffered (32KB)

    const int rowA  = batch0 + (l & 15);        // poll row (A-frag row = batch)
    const int rowD0 = batch0 + (l >> 4) * 4;    // D-frag row base (+j)
    const unsigned short* xa = (const unsigned short*)xact;

    f32x4 c = {0.f, 0.f, 0.f, 0.f};
    bool dead = false;

    // prefetch xact for s=0
    unsigned short xw[4];
#pragma unroll
    for (int j = 0; j < 4; ++j)
        xw[j] = xa[((size_t)0 * 64 + rowD0 + j) * 2048 + g * 512 + hcol];

    for (int s = 0; s < T_STEPS; ++s) {
        // ---- prefetch xact for s+1 BEFORE the poll (overlaps HBM latency) ----
        unsigned short xwn[4];
        if (s + 1 < T_STEPS) {
#pragma unroll
            for (int j = 0; j < 4; ++j)
                xwn[j] = xa[((size_t)(s + 1) * 64 + rowD0 + j) * 2048 + g * 512 + hcol];
        }

        // ---- poll K-quarter v of h_s: 16 x 8B batched, ONE vmcnt wait ----
        unsigned long long q[16];
        {
            const unsigned* hp = hbuf + (s & 1) * (NBATCH * HID)
                               + rowA * HID + v * 128 + (l >> 4) * 8;
            const unsigned long long tagpat =
                ((unsigned long long)(unsigned)s << 16) |
                ((unsigned long long)(unsigned)s << 48);
            int spin = 0;
            while (true) {
                asm volatile(
                    "global_load_dwordx2 %[q0],  %[p], off sc0 sc1\n\t"
                    "global_load_dwordx2 %[q1],  %[p], off offset:8 sc0 sc1\n\t"
                    "global_load_dwordx2 %[q2],  %[p], off offset:16 sc0 sc1\n\t"
                    "global_load_dwordx2 %[q3],  %[p], off offset:24 sc0 sc1\n\t"
                    "global_load_dwordx2 %[q4],  %[p], off offset:128 sc0 sc1\n\t"
                    "global_load_dwordx2 %[q5],  %[p], off offset:136 sc0 sc1\n\t"
                    "global_load_dwordx2 %[q6],  %[p], off offset:144 sc0 sc1\n\t"
                    "global_load_dwordx2 %[q7],  %[p], off offset:152 sc0 sc1\n\t"
                    "global_load_dwordx2 %[q8],  %[p], off offset:256 sc0 sc1\n\t"
                    "global_load_dwordx2 %[q9],  %[p], off offset:264 sc0 sc1\n\t"
                    "global_load_dwordx2 %[q10], %[p], off offset:272 sc0 sc1\n\t"
                    "global_load_dwordx2 %[q11], %[p], off offset:280 sc0 sc1\n\t"
                    "global_load_dwordx2 %[q12], %[p], off offset:384 sc0 sc1\n\t"
                    "global_load_dwordx2 %[q13], %[p], off offset:392 sc0 sc1\n\t"
                    "global_load_dwordx2 %[q14], %[p], off offset:400 sc0 sc1\n\t"
                    "global_load_dwordx2 %[q15], %[p], off offset:408 sc0 sc1\n\t"
                    "s_waitcnt vmcnt(0)"
                    : [q0]"=v"(q[0]),  [q1]"=v"(q[1]),  [q2]"=v"(q[2]),  [q3]"=v"(q[3]),
                      [q4]"=v"(q[4]),  [q5]"=v"(q[5]),  [q6]"=v"(q[6]),  [q7]"=v"(q[7]),
                      [q8]"=v"(q[8]),  [q9]"=v"(q[9]),  [q10]"=v"(q[10]),[q11]"=v"(q[11]),
                      [q12]"=v"(q[12]),[q13]"=v"(q[13]),[q14]"=v"(q[14]),[q15]"=v"(q[15])
                    : [p]"v"(hp)
                    : "memory");
                unsigned long long m = 0;
#pragma unroll
                for (int u = 0; u < 16; ++u)
                    m |= (q[u] ^ tagpat) & 0xFFFF0000FFFF0000ULL;
                if (__all(m == 0) || dead) break;
                if (++spin > (1 << 17)) dead = true;
                else if (spin > 8) __builtin_amdgcn_s_sleep(1);
            }
        }

        // ---- pack (strip tags) + ds_write frag-order ----
#pragma unroll
        for (int sub = 0; sub < 4; ++sub) {
            u32x4 wd;
#pragma unroll
            for (int p = 0; p < 4; ++p)
                wd[p] = __builtin_amdgcn_perm(
                    (unsigned)(q[sub * 4 + p] >> 32), (unsigned)q[sub * 4 + p],
                    0x05040100u);
            *(u32x4*)&alds[s & 1][v * 4 + sub][l][0] = wd;
        }
        __syncthreads();   // A-frags ready (single barrier per step)

        // ---- 16 MFMA over K=512, 2 chains ----
        f32x4 acc0 = {0.f,0.f,0.f,0.f}, acc1 = {0.f,0.f,0.f,0.f};
#pragma unroll
        for (int kk = 0; kk < 16; kk += 2) {
            bf16x8 a0 = *(const bf16x8*)&alds[s & 1][kk][l][0];
            bf16x8 a1 = *(const bf16x8*)&alds[s & 1][kk + 1][l][0];
            acc0 = __builtin_amdgcn_mfma_f32_16x16x32_bf16(a0, wfr[kk],     acc0, 0, 0, 0);
            acc1 = __builtin_amdgcn_mfma_f32_16x16x32_bf16(a1, wfr[kk + 1], acc1, 0, 0, 0);
        }
        f32x4 pre = acc0 + acc1;

        // ---- unified activation (this lane's gate, 4 rows) ----
        f32x4 own;
#pragma unroll
        for (int j = 0; j < 4; ++j) {
            float vv = pre[j] + __uint_as_float((unsigned)xw[j] << 16) + bias;
            float e  = __builtin_amdgcn_exp2f(Kk * vv);
            own[j]   = __builtin_fmaf(Aa, __builtin_amdgcn_rcpf(1.f + e), Cc);
        }
#pragma unroll
        for (int j = 0; j < 4; ++j) xw[j] = xwn[j];

        // ---- in-wave XOR butterfly: gather f,i,o,C (lanes l^4, l^8, l^12) ----
        f32x4 r1 = shfx4(own, 4);
        f32x4 r2 = shfx4(own, 8);
        f32x4 r3 = shfx4(r1, 8);
        f32x4 fv = (g == 0) ? own : (g == 1) ? r1 : (g == 2) ? r2 : r3;
        f32x4 iv = (g == 0) ? r1 : (g == 1) ? own : (g == 2) ? r3 : r2;
        f32x4 ov = (g == 0) ? r2 : (g == 1) ? r3 : (g == 2) ? own : r1;
        f32x4 Cv = (g == 0) ? r3 : (g == 1) ? r2 : (g == 2) ? r1 : own;

        // ---- c update (4x lane-redundant, deterministic) ----
        c = fv * c + iv * Cv;

        // ---- publish: this lane stores row j == its gate id ----
        float cg  = (g == 0) ? c[0] : (g == 1) ? c[1] : (g == 2) ? c[2] : c[3];
        float og  = (g == 0) ? ov[0] : (g == 1) ? ov[1] : (g == 2) ? ov[2] : ov[3];
        float e2  = __builtin_amdgcn_exp2f(-2.885390082f * cg);
        float th  = __builtin_fmaf(2.f, __builtin_amdgcn_rcpf(1.f + e2), -1.f);
        float h   = og * th;
        int   row = rowD0 + g;
        if (s == T_STEPS - 1) {
            out[row * HID + hcol] = h;
        } else {
            unsigned* hd = hbuf + ((s + 1) & 1) * (NBATCH * HID);
            __hip_atomic_store(&hd[row * HID + hcol],
                               ((unsigned)(s + 1) << 16) |
                               (unsigned)(unsigned short)f2bf(h),
                               __ATOMIC_RELAXED, __HIP_MEMORY_SCOPE_AGENT);
        }
    }
}

extern "C" void kernel_launch(void* const* d_in, const int* in_sizes, int n_in,
                              void* d_out, int out_size, void* d_ws, size_t ws_size,
                              hipStream_t stream) {
    const float* x  = (const float*)d_in[0];
    const float* Wf = (const float*)d_in[1];
    const float* bf = (const float*)d_in[2];
    const float* Wi = (const float*)d_in[3];
    const float* bi = (const float*)d_in[4];
    const float* Wo = (const float*)d_in[5];
    const float* bo = (const float*)d_in[6];
    const float* Wc = (const float*)d_in[7];
    const float* bc = (const float*)d_in[8];

    if (ws_size < WS_NEED) return;   // loud failure: out stays poison

    char*     ws     = (char*)d_ws;
    short*    whfrag = (short*)(ws + WS_WHF);
    short*    wxT    = (short*)(ws + WS_WXT);
    unsigned* hbuf   = (unsigned*)(ws + WS_HB);
    short*    xbf    = (short*)(ws + WS_XBF);
    short*    xact   = (short*)(ws + WS_XACT);

    prep_zero<<<dim3(256),  dim3(256), 0, stream>>>(hbuf);
    prep_xbf <<<dim3(8192), dim3(256), 0, stream>>>(x, xbf);
    prep_wx  <<<dim3(512),  dim3(256), 0, stream>>>(Wf, Wi, Wo, Wc, wxT);
    prep_wh  <<<dim3(512),  dim3(256), 0, stream>>>(Wf, Wi, Wo, Wc, whfrag);
    xgemm    <<<dim3(16, 256), dim3(256), 0, stream>>>(xbf, wxT, xact);
    lstm_rec <<<dim3(NCL * WPC), dim3(256), 0, stream>>>(
        xact, bf, bi, bo, bc, whfrag, hbuf, (float*)d_out);
}